// Round 9
// baseline (180.750 us; speedup 1.0000x reference)
//
#include <hip/hip_runtime.h>
#include <math.h>

typedef __attribute__((ext_vector_type(8))) short bf16x8;   // 8 bf16 = 4 VGPRs (MFMA A/B frag)
typedef __attribute__((ext_vector_type(4))) float f32x4;    // MFMA C/D frag
typedef __attribute__((ext_vector_type(4))) unsigned int u32x4;
typedef unsigned short u16;
typedef unsigned int u32;

// Problem: B=8, N=1024, C=768, H=8, hd=96.  BH=64 combined batch-heads.

__device__ __forceinline__ u16 f2b(float f) {               // fp32 -> bf16 RNE
  u32 u = __float_as_uint(f);
  return (u16)((u + 0x7fffu + ((u >> 16) & 1u)) >> 16);
}
__device__ __forceinline__ float b2f(u16 h) {
  return __uint_as_float(((u32)h) << 16);
}
__device__ __forceinline__ int swz(int m) { return (m ^ (m >> 2)) & 3; }

__device__ __forceinline__ void async16(const void* g, void* l) {
  __builtin_amdgcn_global_load_lds((const __attribute__((address_space(1))) u32*)g,
                                   (__attribute__((address_space(3))) u32*)l, 16, 0, 0);
}

// counted vmcnt waits (immediate must be literal in the asm string)
template<int N> __device__ __forceinline__ void wait_vmcnt();
template<> __device__ __forceinline__ void wait_vmcnt<0>() {
  asm volatile("s_waitcnt vmcnt(0)" ::: "memory");
}
template<> __device__ __forceinline__ void wait_vmcnt<3>() {
  asm volatile("s_waitcnt vmcnt(3)" ::: "memory");
}

// ---------------- prep: cast x, transpose+cast w_qkv and w_proj -------------
__global__ __launch_bounds__(256) void prep_kernel(const float* __restrict__ x,
                                                   const float* __restrict__ w_qkv,
                                                   const float* __restrict__ w_proj,
                                                   u16* __restrict__ xb,
                                                   u16* __restrict__ wqkvT,
                                                   u16* __restrict__ wprojT) {
  __shared__ float t[32][33];
  const int blk = blockIdx.x;
  if (blk < 6144) {                       // cast x -> bf16
    const int idx = blk * 256 + threadIdx.x;
    const float4 v = ((const float4*)x)[idx];
    uint2 o;
    o.x = (u32)f2b(v.x) | ((u32)f2b(v.y) << 16);
    o.y = (u32)f2b(v.z) | ((u32)f2b(v.w) << 16);
    ((uint2*)xb)[idx] = o;
    return;
  }
  const float* in; u16* out; int R, C, bx, by;
  if (blk < 6144 + 1728) {                // w_qkv [768,2304] -> [2304,768]
    const int rem = blk - 6144;
    in = w_qkv; out = wqkvT; R = 768; C = 2304; bx = rem % 72; by = rem / 72;
  } else {                                // w_proj [768,768] -> [768,768]
    const int rem = blk - 6144 - 1728;
    in = w_proj; out = wprojT; R = 768; C = 768; bx = rem % 24; by = rem / 24;
  }
  const int c0 = bx * 32, r0 = by * 32;
  const int tc = threadIdx.x & 31, tr = threadIdx.x >> 5;
#pragma unroll
  for (int j = 0; j < 4; ++j)
    t[tr + j * 8][tc] = in[(size_t)(r0 + tr + j * 8) * C + c0 + tc];
  __syncthreads();
#pragma unroll
  for (int j = 0; j < 4; ++j)
    out[(size_t)(c0 + tr + j * 8) * R + r0 + tc] = f2b(t[tc][tr + j * 8]);
}

// ---------------- BK=32 2-barrier GEMM core (qkv) ---------------------------
// REVERTED to the round-3 structure: best measured across six variants
// (44.28us, FETCH 20MB, occ 23% -- dbuf/8wave/counted-3buf/BK64 all landed
// 44.4-49.2).  qkv sits ON the m97-structure reference curve for this size;
// further scheduling rounds are not the lever (m232: 8-phase null at
// 128-class tiles, and NT=192 is forced by the head-local l2norm epilogue).
// Unified LDS granule array: A slots [0,512), B slots [512,512+NT*4).
// Granule XOR swizzle x(m)=(m^(m>>2))&3 keeps frag ds_read_b128 clean while
// staging stays lane-contiguous for global_load_lds (wave-uniform base).
template<int NT>
__device__ __forceinline__ void gemm_core2b(const u16* __restrict__ A,
                                            const u16* __restrict__ Bt,
                                            int m0, int n0, f32x4 acc[4][NT / 32]) {
  constexpr int JT = NT / 32;
  constexpr int NINST = (512 + NT * 4) / 256;
  __shared__ u16 Sm[(512 + NT * 4) * 8];
  const int tid = threadIdx.x;
  const int w = tid >> 6, lane = tid & 63;
  const int i15 = lane & 15, quad = lane >> 4;
  const int wm = (w >> 1) * 64, wn = (w & 1) * (NT / 2);
  const int sw = quad ^ swz(i15);

#pragma unroll
  for (int i = 0; i < 4; ++i)
#pragma unroll
    for (int j = 0; j < JT; ++j) acc[i][j] = (f32x4){0.f, 0.f, 0.f, 0.f};

  for (int k0 = 0; k0 < 768; k0 += 32) {
    __syncthreads();
#pragma unroll
    for (int inst = 0; inst < NINST; ++inst) {
      const int s = inst * 256 + tid;          // granule slot (per lane)
      const u16* src;
      if (inst < 2) {                          // A region (slots < 512)
        const int m = s >> 2, e = s & 3;
        src = A + ((size_t)(m0 + m) * 768 + k0 + (e ^ swz(m)) * 8);
      } else {                                 // B region
        const int s2 = s - 512;
        const int n = s2 >> 2, e = s2 & 3;
        src = Bt + ((size_t)(n0 + n) * 768 + k0 + (e ^ swz(n)) * 8);
      }
      async16(src, (void*)(Sm + (size_t)(inst * 256 + w * 64) * 8));
    }
    __syncthreads();                           // drains vmcnt before reads
    bf16x8 af[4], bf[JT];
#pragma unroll
    for (int i = 0; i < 4; ++i)
      af[i] = *(const bf16x8*)(Sm + ((size_t)(wm + i * 16 + i15) * 4 + sw) * 8);
#pragma unroll
    for (int j = 0; j < JT; ++j)
      bf[j] = *(const bf16x8*)(Sm + ((size_t)512 + (wn + j * 16 + i15) * 4 + sw) * 8);
#pragma unroll
    for (int i = 0; i < 4; ++i)
#pragma unroll
      for (int j = 0; j < JT; ++j)
        acc[i][j] = __builtin_amdgcn_mfma_f32_16x16x32_bf16(af[i], bf[j], acc[i][j], 0, 0, 0);
  }
}

// ---------------- BK=32 3-buffer counted-vmcnt core (proj) ------------------
// Round-6 core, kept for proj where it measurably helped (36KB -> 4 blk/CU).
template<int NT>
__device__ __forceinline__ void gemm_core_c3(const u16* __restrict__ A,
                                             const u16* __restrict__ Bt,
                                             int m0, int n0, f32x4 acc[4][NT / 32]) {
  constexpr int JT = NT / 32;
  constexpr int NG = 512 + NT * 4;               // granules per K-tile
  constexpr int NINST = NG / 256;                // async16 per thread per tile
  __shared__ u16 Sm[3 * NG * 8];
  const int tid = threadIdx.x;
  const int w = tid >> 6, lane = tid & 63;
  const int i15 = lane & 15, quad = lane >> 4;
  const int wm = (w >> 1) * 64, wn = (w & 1) * (NT / 2);
  const int sw = quad ^ swz(i15);

#pragma unroll
  for (int i = 0; i < 4; ++i)
#pragma unroll
    for (int j = 0; j < JT; ++j) acc[i][j] = (f32x4){0.f, 0.f, 0.f, 0.f};

  const u16* gsrc[NINST];
#pragma unroll
  for (int inst = 0; inst < NINST; ++inst) {
    const int s = inst * 256 + tid;              // granule slot (per lane)
    if (s < 512) {                               // A region
      const int m = s >> 2, e = s & 3;
      gsrc[inst] = A + ((size_t)(m0 + m) * 768 + (e ^ swz(m)) * 8);
    } else {                                     // B region
      const int s2 = s - 512;
      const int n = s2 >> 2, e = s2 & 3;
      gsrc[inst] = Bt + ((size_t)(n0 + n) * 768 + (e ^ swz(n)) * 8);
    }
  }

  auto stage = [&](int bsel) {
#pragma unroll
    for (int inst = 0; inst < NINST; ++inst) {
      async16(gsrc[inst], (void*)(Sm + ((size_t)bsel * NG + inst * 256 + w * 64) * 8));
      gsrc[inst] += 32;
    }
  };

  stage(0);
  stage(1);

  for (int t = 0; t < 24; ++t) {
    if (t < 23) wait_vmcnt<NINST>();             // tile t landed; t+1 in flight
    else        wait_vmcnt<0>();                 // last tile: full drain
    __builtin_amdgcn_s_barrier();                // all waves' t-loads visible
    __builtin_amdgcn_sched_barrier(0);           // pin: nothing hoists above
    if (t < 22) stage((t + 2) % 3);              // out back to 2*NINST
    const u16* buf = Sm + (size_t)(t % 3) * NG * 8;
    bf16x8 af[4], bf[JT];
#pragma unroll
    for (int i = 0; i < 4; ++i)
      af[i] = *(const bf16x8*)(buf + ((size_t)(wm + i * 16 + i15) * 4 + sw) * 8);
#pragma unroll
    for (int j = 0; j < JT; ++j)
      bf[j] = *(const bf16x8*)(buf + ((size_t)512 + (wn + j * 16 + i15) * 4 + sw) * 8);
#pragma unroll
    for (int i = 0; i < 4; ++i)
#pragma unroll
      for (int j = 0; j < JT; ++j)
        acc[i][j] = __builtin_amdgcn_mfma_f32_16x16x32_bf16(af[i], bf[j], acc[i][j], 0, 0, 0);
  }
}

// ---------------- qkv GEMM + fused L2norm/temp epilogue ---------------------
// Tile 128x192: N-tile = exactly 2 heads -> each wave owns one head's full
// 96-d rows. Rows live in 16 lanes sharing quad -> sumsq = in-thread over jt
// + shfl_xor(1,2,4,8). q gets temp[h] folded; v written transposed (packed).
__global__ __launch_bounds__(256, 3) void qkv_gemm_kernel(
    const u16* __restrict__ xb, const u16* __restrict__ wT,
    const float* __restrict__ temp,
    u16* __restrict__ q, u16* __restrict__ k, u16* __restrict__ vT) {
  f32x4 acc[4][6];
  const int bid = blockIdx.x;                 // 768 blocks = 3/CU exact
  const int xcd = bid & 7, slot = bid >> 3;   // 96 slots per XCD
  const int mb = xcd * 8 + slot / 12, nb = slot % 12;
  const int m0 = mb * 128, n0 = nb * 192;
  gemm_core2b<192>(xb, wT, m0, n0, acc);

  const int tid = threadIdx.x, w = tid >> 6, lane = tid & 63;
  const int i15 = lane & 15, quad = lane >> 4;
  const int wm = (w >> 1) * 64;
  const int three = nb >> 2;                  // 0=q, 1=k, 2=v
  const int h = ((nb & 3) << 1) + (w & 1);    // wave-uniform head

  if (three < 2) {
    u16* dst = three ? k : q;
    const float sc_extra = three ? 1.f : temp[h];
#pragma unroll
    for (int it = 0; it < 4; ++it) {
#pragma unroll
      for (int r = 0; r < 4; ++r) {
        float s = 0.f;
#pragma unroll
        for (int jt = 0; jt < 6; ++jt) s += acc[it][jt][r] * acc[it][jt][r];
        s += __shfl_xor(s, 1); s += __shfl_xor(s, 2);
        s += __shfl_xor(s, 4); s += __shfl_xor(s, 8);
        const float scale = sc_extra / fmaxf(sqrtf(s), 1e-12f);
        const int m = m0 + wm + it * 16 + quad * 4 + r;
        const int b = m >> 10, n = m & 1023;
        u16* rowp = dst + ((size_t)(b * 8 + h) * 1024 + n) * 96;
#pragma unroll
        for (int jt = 0; jt < 6; ++jt)
          rowp[jt * 16 + i15] = f2b(acc[it][jt][r] * scale);
      }
    }
  } else {
#pragma unroll
    for (int it = 0; it < 4; ++it) {
      const int mb4 = m0 + wm + it * 16 + quad * 4;
      const int b = mb4 >> 10, nbase = mb4 & 1023;
#pragma unroll
      for (int jt = 0; jt < 6; ++jt) {
        const int d = jt * 16 + i15;
        uint2 pk;
        pk.x = (u32)f2b(acc[it][jt][0]) | ((u32)f2b(acc[it][jt][1]) << 16);
        pk.y = (u32)f2b(acc[it][jt][2]) | ((u32)f2b(acc[it][jt][3]) << 16);
        *(uint2*)(vT + ((size_t)(b * 8 + h) * 96 + d) * 1024 + nbase) = pk;
      }
    }
  }
}

// ---------------- fused attention, bf16 MFMA, no-max online softmax ---------
// 128 q-rows/block, grid 512, bh = blockIdx&63 (8 q-blocks of one bh share an
// XCD; K/V L2-resident ~3 MB/XCD).  512 threads = 8 waves x 16 q-rows.
// ROUND-9: S/PV cross-tile overlap (T15-class, m214v36 +7-11%): per iter t,
// run S(t+1) CONCURRENTLY with PV(t).  The P hazard is broken by pre-reading
// the two pa fragments of P(t) into registers before S(t+1) overwrites P
// (same-wave DS ops are in-order: reads issued first return old data).  K
// needs depth-2 prefetch (S(t+1) consumes K(t+1) inside iter t) -> K gets 3
// buffers, V keeps 2, P single.  LDS 36+24+16 = 76KB -> 2 blk/CU unchanged;
// memory behavior identical (same tiles, same bh->XCD mapping).
// Buffer safety per iter t (all distinct):  read K[(t+1)%3], write K[(t+2)%3]
// (holds K(t-1), last read iter t-2);  read V[t&1], write V[(t+1)&1] (holds
// V(t-1), last read iter t-1, freed by this iter's sync).
__global__ __launch_bounds__(512, 2) void attn_kernel(
    const u16* __restrict__ q, const u16* __restrict__ kk,
    const u16* __restrict__ vT, u16* __restrict__ ctx) {
  // u16 offsets: K0/K1/K2 @ 0/6144/12288; V0/V1 @ 18432/24576; P @ 30720
  __shared__ u16 smem[38912];
  const int tid = threadIdx.x, w = tid >> 6, lane = tid & 63;
  const int i15 = lane & 15, quad = lane >> 4;
  const int xs = swz(i15);
  const int bh = blockIdx.x & 63, qbase = (blockIdx.x >> 6) * 128;
  const int b = bh >> 3, h = bh & 7;
  u16* Pw = smem + 30720 + w * 1024;   // per-wave P: 128 granules (16 rows x 64 keys)

  bf16x8 qf[3];
  {
    const int qrow = qbase + w * 16 + i15;
    const u16* qp = q + ((size_t)bh * 1024 + qrow) * 96 + quad * 8;
#pragma unroll
    for (int c = 0; c < 3; ++c) qf[c] = *(const bf16x8*)(qp + c * 32);
  }

  // Per-thread staging source bases (tile 0); K granule slot s: inst0 s=tid,
  // inst1 s=512+tid (only tid<256 active -> waves 0-3, wave-uniform branch).
  //   K slot s<768:  key=(s&255)>>2, c=s>>8 -> row key, octet c*4+((s&3)^swz(key))
  //   V slot s2<768: r=s2>>2, c2=r>=96, d=r-96*c2 -> row d, col c2*32+((s2&3)^swz(d))*8
  const u16 *kb0, *kb1, *vb0, *vb1;
  {
    int s = tid, key = (s & 255) >> 2, c = s >> 8;
    kb0 = kk + ((size_t)bh * 1024 + key) * 96 + (c * 4 + ((s & 3) ^ swz(key))) * 8;
    s = 512 + tid; key = (s & 255) >> 2; c = s >> 8;
    kb1 = kk + ((size_t)bh * 1024 + key) * 96 + (c * 4 + ((s & 3) ^ swz(key))) * 8;
    int s2 = tid, r = s2 >> 2, c2 = (r >= 96), d = r - 96 * c2;
    vb0 = vT + ((size_t)bh * 96 + d) * 1024 + c2 * 32 + ((s2 & 3) ^ swz(d)) * 8;
    s2 = 512 + tid; r = s2 >> 2; c2 = (r >= 96); d = r - 96 * c2;
    vb1 = vT + ((size_t)bh * 96 + d) * 1024 + c2 * 32 + ((s2 & 3) ^ swz(d)) * 8;
  }
  auto stageK = [&](int tt, int kbuf) {
    u16* dst = smem + kbuf * 6144;
    async16(kb0 + (size_t)tt * 64 * 96, (void*)(dst + (size_t)(w * 64) * 8));
    if (tid < 256)
      async16(kb1 + (size_t)tt * 64 * 96, (void*)(dst + (size_t)(512 + w * 64) * 8));
  };
  auto stageV = [&](int tt, int vbuf) {
    u16* dst = smem + 18432 + vbuf * 6144;
    async16(vb0 + tt * 64, (void*)(dst + (size_t)(w * 64) * 8));
    if (tid < 256)
      async16(vb1 + tt * 64, (void*)(dst + (size_t)(512 + w * 64) * 8));
  };

  f32x4 o[6];
#pragma unroll
  for (int dt = 0; dt < 6; ++dt) o[dt] = (f32x4){0.f, 0.f, 0.f, 0.f};
  float l = 0.f;

  auto S_phase = [&](const u16* Kb) {
#pragma unroll
    for (int kt = 0; kt < 4; ++kt) {
      bf16x8 af[3];
#pragma unroll
      for (int c = 0; c < 3; ++c)
        af[c] = *(const bf16x8*)(Kb + ((size_t)((c * 64 + kt * 16 + i15) * 4) + (quad ^ xs)) * 8);
      f32x4 s = (f32x4){0.f, 0.f, 0.f, 0.f};
#pragma unroll
      for (int c = 0; c < 3; ++c)
        s = __builtin_amdgcn_mfma_f32_16x16x32_bf16(af[c], qf[c], s, 0, 0, 0);
      const float e0 = __expf(s[0]), e1 = __expf(s[1]);
      const float e2 = __expf(s[2]), e3 = __expf(s[3]);
      l += (e0 + e1) + (e2 + e3);
      uint2 pk;
      pk.x = (u32)f2b(e0) | ((u32)f2b(e1) << 16);
      pk.y = (u32)f2b(e2) | ((u32)f2b(e3) << 16);
      const int pg = (kt & 1) * 2 + (quad >> 1);
      *(uint2*)(Pw + (size_t)(((kt >> 1) * 16 + i15) * 4 + (pg ^ xs)) * 8
                    + (quad & 1) * 4) = pk;
    }
  };

  // prologue: K0/V0 staged+drained; K1/V1 in flight; S(0) -> P
  stageK(0, 0); stageV(0, 0);
  __syncthreads();
  stageK(1, 1); stageV(1, 1);
  S_phase(smem);

  for (int t = 0; t < 16; ++t) {
    // pre-read P(t) fragments (own-wave, written by S(t) in program order)
    const bf16x8 pa0 = *(const bf16x8*)(Pw + (size_t)((i15 * 4) + (quad ^ xs)) * 8);
    const bf16x8 pa1 = *(const bf16x8*)(Pw + (size_t)(((16 + i15) * 4) + (quad ^ xs)) * 8);
    __syncthreads();                 // drains prev-iter stages; frees old buffers
    if (t < 14) stageK(t + 2, (t + 2) % 3);
    if (t < 15) stageV(t + 1, (t + 1) & 1);
    if (t < 15) S_phase(smem + ((t + 1) % 3) * 6144);   // writes P(t+1)
    // PV(t): pa regs + V[t&1]  (independent of S(t+1) -> co-scheduled)
    const u16* Vb = smem + 18432 + (t & 1) * 6144;
#pragma unroll
    for (int dt = 0; dt < 6; ++dt) {
      const bf16x8 vb = *(const bf16x8*)(Vb + ((size_t)((dt * 16 + i15) * 4) + (quad ^ xs)) * 8);
      o[dt] = __builtin_amdgcn_mfma_f32_16x16x32_bf16(pa0, vb, o[dt], 0, 0, 0);
    }
#pragma unroll
    for (int dt = 0; dt < 6; ++dt) {
      const bf16x8 vb = *(const bf16x8*)(Vb + ((size_t)(((96 + dt * 16 + i15) * 4)) + (quad ^ xs)) * 8);
      o[dt] = __builtin_amdgcn_mfma_f32_16x16x32_bf16(pa1, vb, o[dt], 0, 0, 0);
    }
  }

  l += __shfl_xor(l, 16); l += __shfl_xor(l, 32);
  __syncthreads();                       // all waves done with K/V/P regions
  u16* scr = smem + w * 1664;            // 16 rows x stride 104 (per-wave)
#pragma unroll
  for (int r = 0; r < 4; ++r) {
    const float linv = 1.f / __shfl(l, quad * 4 + r);
    const int row16 = quad * 4 + r;
#pragma unroll
    for (int dt = 0; dt < 6; ++dt)
      scr[row16 * 104 + dt * 16 + i15] = f2b(o[dt][r] * linv);
  }
#pragma unroll
  for (int jj = 0; jj < 3; ++jj) {
    const int id = jj * 64 + lane;
    const int row16 = id / 12, g = id - row16 * 12;
    const int grow = b * 1024 + qbase + w * 16 + row16;
    *(uint4*)(ctx + (size_t)grow * 768 + h * 96 + g * 8) =
        *(const uint4*)(scr + row16 * 104 + g * 8);
  }
}

// ---------------- proj GEMM: 128x64 tiles, ctx @ wT + bias -> out fp32 ------
// 3-buffer counted-vmcnt core, LDS 36KB -> 4 blocks/CU (round-6, kept: total
// improved ~7us from this even as qkv regressed).
__global__ __launch_bounds__(256, 4) void proj_gemm_kernel(
    const u16* __restrict__ ctx, const u16* __restrict__ wT,
    const float* __restrict__ bias, float* __restrict__ out) {
  f32x4 acc[4][2];
  const int bid = blockIdx.x;                 // 768 blocks
  const int xcd = bid & 7, slot = bid >> 3;   // 96 slots per XCD
  const int mb = xcd * 8 + slot / 12, nb = slot % 12;
  const int m0 = mb * 128, n0 = nb * 64;
  gemm_core_c3<64>(ctx, wT, m0, n0, acc);

  const int tid = threadIdx.x, w = tid >> 6, lane = tid & 63;
  const int i15 = lane & 15, quad = lane >> 4;
  const int wm = (w >> 1) * 64, wn = (w & 1) * 32;
#pragma unroll
  for (int jt = 0; jt < 2; ++jt) {
    const int c = n0 + wn + jt * 16 + i15;
    const float bb = bias[c];
#pragma unroll
    for (int it = 0; it < 4; ++it) {
#pragma unroll
      for (int r = 0; r < 4; ++r) {
        const int m = m0 + wm + it * 16 + quad * 4 + r;
        out[(size_t)m * 768 + c] = acc[it][jt][r] + bb;
      }
    }
  }
}

// ---------------- host launcher --------------------------------------------
extern "C" void kernel_launch(void* const* d_in, const int* in_sizes, int n_in,
                              void* d_out, int out_size, void* d_ws, size_t ws_size,
                              hipStream_t stream) {
  const float* x      = (const float*)d_in[0];   // [8,1024,768]
  const float* w_qkv  = (const float*)d_in[1];   // [768,2304]
  const float* temp   = (const float*)d_in[2];   // [8]
  const float* w_proj = (const float*)d_in[3];   // [768,768]
  const float* b_proj = (const float*)d_in[4];   // [768]

  u16* ws      = (u16*)d_ws;
  u16* xb      = ws;                     // 8192*768
  u16* wqkvT   = xb + 6291456;           // 2304*768
  u16* qb      = wqkvT + 1769472;        // 64*1024*96
  u16* kb      = qb + 6291456;
  u16* vTb     = kb + 6291456;           // 64*96*1024 (transposed)
  u16* ctxb    = vTb + 6291456;          // 8192*768
  u16* wprojT  = ctxb + 6291456;         // 768*768

  prep_kernel<<<8448, 256, 0, stream>>>(x, w_qkv, w_proj, xb, wqkvT, wprojT);
  qkv_gemm_kernel<<<768, 256, 0, stream>>>(xb, wqkvT, temp, qb, kb, vTb);
  attn_kernel<<<512, 512, 0, stream>>>(qb, kb, vTb, ctxb);
  proj_gemm_kernel<<<768, 256, 0, stream>>>(ctxb, wprojT, b_proj, (float*)d_out);
}

// Round 10
// 179.119 us; speedup vs baseline: 1.0091x; 1.0091x over previous
//
#include <hip/hip_runtime.h>
#include <hip/hip_bf16.h>
#include <math.h>

typedef __attribute__((ext_vector_type(8))) short bf16x8;   // 8 bf16 = 4 VGPRs (MFMA A/B frag)
typedef __attribute__((ext_vector_type(4))) float f32x4;    // MFMA C/D frag
typedef __attribute__((ext_vector_type(4))) unsigned int u32x4;
typedef unsigned short u16;
typedef unsigned int u32;

// Problem: B=8, N=1024, C=768, H=8, hd=96.  BH=64 combined batch-heads.

__device__ __forceinline__ u16 f2b(float f) {               // fp32 -> bf16 RNE (bit-twiddle)
  u32 u = __float_as_uint(f);
  return (u16)((u + 0x7fffu + ((u >> 16) & 1u)) >> 16);
}
__device__ __forceinline__ u16 f2bq(float f) {              // native v_cvt (RNE on gfx950)
  __hip_bfloat16 h = __float2bfloat16(f);
  return __bfloat16_as_ushort(h);
}
__device__ __forceinline__ float b2f(u16 h) {
  return __uint_as_float(((u32)h) << 16);
}
__device__ __forceinline__ int swz(int m) { return (m ^ (m >> 2)) & 3; }

__device__ __forceinline__ void async16(const void* g, void* l) {
  __builtin_amdgcn_global_load_lds((const __attribute__((address_space(1))) u32*)g,
                                   (__attribute__((address_space(3))) u32*)l, 16, 0, 0);
}

// counted vmcnt waits (immediate must be literal in the asm string)
template<int N> __device__ __forceinline__ void wait_vmcnt();
template<> __device__ __forceinline__ void wait_vmcnt<0>() {
  asm volatile("s_waitcnt vmcnt(0)" ::: "memory");
}
template<> __device__ __forceinline__ void wait_vmcnt<3>() {
  asm volatile("s_waitcnt vmcnt(3)" ::: "memory");
}

// ---------------- prep: cast x, transpose+cast w_qkv and w_proj -------------
__global__ __launch_bounds__(256) void prep_kernel(const float* __restrict__ x,
                                                   const float* __restrict__ w_qkv,
                                                   const float* __restrict__ w_proj,
                                                   u16* __restrict__ xb,
                                                   u16* __restrict__ wqkvT,
                                                   u16* __restrict__ wprojT) {
  __shared__ float t[32][33];
  const int blk = blockIdx.x;
  if (blk < 6144) {                       // cast x -> bf16
    const int idx = blk * 256 + threadIdx.x;
    const float4 v = ((const float4*)x)[idx];
    uint2 o;
    o.x = (u32)f2b(v.x) | ((u32)f2b(v.y) << 16);
    o.y = (u32)f2b(v.z) | ((u32)f2b(v.w) << 16);
    ((uint2*)xb)[idx] = o;
    return;
  }
  const float* in; u16* out; int R, C, bx, by;
  if (blk < 6144 + 1728) {                // w_qkv [768,2304] -> [2304,768]
    const int rem = blk - 6144;
    in = w_qkv; out = wqkvT; R = 768; C = 2304; bx = rem % 72; by = rem / 72;
  } else {                                // w_proj [768,768] -> [768,768]
    const int rem = blk - 6144 - 1728;
    in = w_proj; out = wprojT; R = 768; C = 768; bx = rem % 24; by = rem / 24;
  }
  const int c0 = bx * 32, r0 = by * 32;
  const int tc = threadIdx.x & 31, tr = threadIdx.x >> 5;
#pragma unroll
  for (int j = 0; j < 4; ++j)
    t[tr + j * 8][tc] = in[(size_t)(r0 + tr + j * 8) * C + c0 + tc];
  __syncthreads();
#pragma unroll
  for (int j = 0; j < 4; ++j)
    out[(size_t)(c0 + tr + j * 8) * R + r0 + tc] = f2b(t[tc][tr + j * 8]);
}

// ---------------- BK=32 2-barrier GEMM core (qkv) ---------------------------
// Best measured across six variants (44.3us, FETCH 20MB, occ 23%; dbuf /
// 8-wave / counted-3buf / BK64 all landed 44.4-49.2).  qkv sits at 26% MFMA,
// ~31% LDS BW, ~24% per-CU L2 BW -- the m97-structure latency plateau; the
// documented escape (8-phase 256-tile) doesn't fit grid/epilogue constraints.
// Unified LDS granule array: A slots [0,512), B slots [512,512+NT*4).
// Granule XOR swizzle x(m)=(m^(m>>2))&3 keeps frag ds_read_b128 clean while
// staging stays lane-contiguous for global_load_lds (wave-uniform base).
template<int NT>
__device__ __forceinline__ void gemm_core2b(const u16* __restrict__ A,
                                            const u16* __restrict__ Bt,
                                            int m0, int n0, f32x4 acc[4][NT / 32]) {
  constexpr int JT = NT / 32;
  constexpr int NINST = (512 + NT * 4) / 256;
  __shared__ u16 Sm[(512 + NT * 4) * 8];
  const int tid = threadIdx.x;
  const int w = tid >> 6, lane = tid & 63;
  const int i15 = lane & 15, quad = lane >> 4;
  const int wm = (w >> 1) * 64, wn = (w & 1) * (NT / 2);
  const int sw = quad ^ swz(i15);

#pragma unroll
  for (int i = 0; i < 4; ++i)
#pragma unroll
    for (int j = 0; j < JT; ++j) acc[i][j] = (f32x4){0.f, 0.f, 0.f, 0.f};

  for (int k0 = 0; k0 < 768; k0 += 32) {
    __syncthreads();
#pragma unroll
    for (int inst = 0; inst < NINST; ++inst) {
      const int s = inst * 256 + tid;          // granule slot (per lane)
      const u16* src;
      if (inst < 2) {                          // A region (slots < 512)
        const int m = s >> 2, e = s & 3;
        src = A + ((size_t)(m0 + m) * 768 + k0 + (e ^ swz(m)) * 8);
      } else {                                 // B region
        const int s2 = s - 512;
        const int n = s2 >> 2, e = s2 & 3;
        src = Bt + ((size_t)(n0 + n) * 768 + k0 + (e ^ swz(n)) * 8);
      }
      async16(src, (void*)(Sm + (size_t)(inst * 256 + w * 64) * 8));
    }
    __syncthreads();                           // drains vmcnt before reads
    bf16x8 af[4], bf[JT];
#pragma unroll
    for (int i = 0; i < 4; ++i)
      af[i] = *(const bf16x8*)(Sm + ((size_t)(wm + i * 16 + i15) * 4 + sw) * 8);
#pragma unroll
    for (int j = 0; j < JT; ++j)
      bf[j] = *(const bf16x8*)(Sm + ((size_t)512 + (wn + j * 16 + i15) * 4 + sw) * 8);
#pragma unroll
    for (int i = 0; i < 4; ++i)
#pragma unroll
      for (int j = 0; j < JT; ++j)
        acc[i][j] = __builtin_amdgcn_mfma_f32_16x16x32_bf16(af[i], bf[j], acc[i][j], 0, 0, 0);
  }
}

// ---------------- BK=32 3-buffer counted-vmcnt core (proj) ------------------
// Round-6 core, kept for proj where it measurably helped (36KB -> 4 blk/CU).
template<int NT>
__device__ __forceinline__ void gemm_core_c3(const u16* __restrict__ A,
                                             const u16* __restrict__ Bt,
                                             int m0, int n0, f32x4 acc[4][NT / 32]) {
  constexpr int JT = NT / 32;
  constexpr int NG = 512 + NT * 4;               // granules per K-tile
  constexpr int NINST = NG / 256;                // async16 per thread per tile
  __shared__ u16 Sm[3 * NG * 8];
  const int tid = threadIdx.x;
  const int w = tid >> 6, lane = tid & 63;
  const int i15 = lane & 15, quad = lane >> 4;
  const int wm = (w >> 1) * 64, wn = (w & 1) * (NT / 2);
  const int sw = quad ^ swz(i15);

#pragma unroll
  for (int i = 0; i < 4; ++i)
#pragma unroll
    for (int j = 0; j < JT; ++j) acc[i][j] = (f32x4){0.f, 0.f, 0.f, 0.f};

  const u16* gsrc[NINST];
#pragma unroll
  for (int inst = 0; inst < NINST; ++inst) {
    const int s = inst * 256 + tid;              // granule slot (per lane)
    if (s < 512) {                               // A region
      const int m = s >> 2, e = s & 3;
      gsrc[inst] = A + ((size_t)(m0 + m) * 768 + (e ^ swz(m)) * 8);
    } else {                                     // B region
      const int s2 = s - 512;
      const int n = s2 >> 2, e = s2 & 3;
      gsrc[inst] = Bt + ((size_t)(n0 + n) * 768 + (e ^ swz(n)) * 8);
    }
  }

  auto stage = [&](int bsel) {
#pragma unroll
    for (int inst = 0; inst < NINST; ++inst) {
      async16(gsrc[inst], (void*)(Sm + ((size_t)bsel * NG + inst * 256 + w * 64) * 8));
      gsrc[inst] += 32;
    }
  };

  stage(0);
  stage(1);

  for (int t = 0; t < 24; ++t) {
    if (t < 23) wait_vmcnt<NINST>();             // tile t landed; t+1 in flight
    else        wait_vmcnt<0>();                 // last tile: full drain
    __builtin_amdgcn_s_barrier();                // all waves' t-loads visible
    __builtin_amdgcn_sched_barrier(0);           // pin: nothing hoists above
    if (t < 22) stage((t + 2) % 3);              // out back to 2*NINST
    const u16* buf = Sm + (size_t)(t % 3) * NG * 8;
    bf16x8 af[4], bf[JT];
#pragma unroll
    for (int i = 0; i < 4; ++i)
      af[i] = *(const bf16x8*)(buf + ((size_t)(wm + i * 16 + i15) * 4 + sw) * 8);
#pragma unroll
    for (int j = 0; j < JT; ++j)
      bf[j] = *(const bf16x8*)(buf + ((size_t)512 + (wn + j * 16 + i15) * 4 + sw) * 8);
#pragma unroll
    for (int i = 0; i < 4; ++i)
#pragma unroll
      for (int j = 0; j < JT; ++j)
        acc[i][j] = __builtin_amdgcn_mfma_f32_16x16x32_bf16(af[i], bf[j], acc[i][j], 0, 0, 0);
  }
}

// ---------------- qkv GEMM + fused L2norm/temp epilogue ---------------------
// Tile 128x192: N-tile = exactly 2 heads -> each wave owns one head's full
// 96-d rows. Rows live in 16 lanes sharing quad -> sumsq = in-thread over jt
// + shfl_xor(1,2,4,8). q gets temp[h] folded; v written transposed (packed).
__global__ __launch_bounds__(256, 3) void qkv_gemm_kernel(
    const u16* __restrict__ xb, const u16* __restrict__ wT,
    const float* __restrict__ temp,
    u16* __restrict__ q, u16* __restrict__ k, u16* __restrict__ vT) {
  f32x4 acc[4][6];
  const int bid = blockIdx.x;                 // 768 blocks = 3/CU exact
  const int xcd = bid & 7, slot = bid >> 3;   // 96 slots per XCD
  const int mb = xcd * 8 + slot / 12, nb = slot % 12;
  const int m0 = mb * 128, n0 = nb * 192;
  gemm_core2b<192>(xb, wT, m0, n0, acc);

  const int tid = threadIdx.x, w = tid >> 6, lane = tid & 63;
  const int i15 = lane & 15, quad = lane >> 4;
  const int wm = (w >> 1) * 64;
  const int three = nb >> 2;                  // 0=q, 1=k, 2=v
  const int h = ((nb & 3) << 1) + (w & 1);    // wave-uniform head

  if (three < 2) {
    u16* dst = three ? k : q;
    const float sc_extra = three ? 1.f : temp[h];
#pragma unroll
    for (int it = 0; it < 4; ++it) {
#pragma unroll
      for (int r = 0; r < 4; ++r) {
        float s = 0.f;
#pragma unroll
        for (int jt = 0; jt < 6; ++jt) s += acc[it][jt][r] * acc[it][jt][r];
        s += __shfl_xor(s, 1); s += __shfl_xor(s, 2);
        s += __shfl_xor(s, 4); s += __shfl_xor(s, 8);
        const float scale = sc_extra / fmaxf(sqrtf(s), 1e-12f);
        const int m = m0 + wm + it * 16 + quad * 4 + r;
        const int b = m >> 10, n = m & 1023;
        u16* rowp = dst + ((size_t)(b * 8 + h) * 1024 + n) * 96;
#pragma unroll
        for (int jt = 0; jt < 6; ++jt)
          rowp[jt * 16 + i15] = f2b(acc[it][jt][r] * scale);
      }
    }
  } else {
#pragma unroll
    for (int it = 0; it < 4; ++it) {
      const int mb4 = m0 + wm + it * 16 + quad * 4;
      const int b = mb4 >> 10, nbase = mb4 & 1023;
#pragma unroll
      for (int jt = 0; jt < 6; ++jt) {
        const int d = jt * 16 + i15;
        uint2 pk;
        pk.x = (u32)f2b(acc[it][jt][0]) | ((u32)f2b(acc[it][jt][1]) << 16);
        pk.y = (u32)f2b(acc[it][jt][2]) | ((u32)f2b(acc[it][jt][3]) << 16);
        *(uint2*)(vT + ((size_t)(b * 8 + h) * 96 + d) * 1024 + nbase) = pk;
      }
    }
  }
}

// ---------------- fused attention, bf16 MFMA, no-max online softmax ---------
// REVERTED to the r3 double-buffered structure (S/PV cross-tile overlap of r9
// was net-negative: attn 43.9- -> 44.7, total +2.4us).  128 q-rows/block,
// grid 512, bh = blockIdx&63 (8 q-blocks of one bh share an XCD; K/V
// L2-resident ~3 MB/XCD).  512 threads = 8 waves x 16 q-rows.
// global_load_lds staging into DOUBLE-BUFFERED KV region, one barrier/tile.
// LDS: 2 x 12288 u16 KV buffers + 8 x 1024 u16 per-wave P = 64 KB -> 2 blk/CU.
// NEW vs r3: (a) native v_cvt bf16 conversions in the S-phase P-pack and the
// epilogue (f2bq; the 5-op bit-twiddle f2b was ~60% of the S-phase VALU work,
// and attn's VALU was its busiest pipe at 38.7% in r9); (b) s_setprio(1)
// around the S and PV MFMA clusters (m191: +4-7% isolated on attn).
__global__ __launch_bounds__(512, 4) void attn_kernel(
    const u16* __restrict__ q, const u16* __restrict__ kk,
    const u16* __restrict__ vT, u16* __restrict__ ctx) {
  __shared__ u16 smem[32768];   // [0,12288) buf0; [12288,24576) buf1; [24576,32768) P
  const int tid = threadIdx.x, w = tid >> 6, lane = tid & 63;
  const int i15 = lane & 15, quad = lane >> 4;
  const int xs = swz(i15);
  const int bh = blockIdx.x & 63, qbase = (blockIdx.x >> 6) * 128;
  const int b = bh >> 3, h = bh & 7;
  u16* Pw = smem + 24576 + w * 1024;   // per-wave P: 128 granules (16 rows x 64 keys)

  bf16x8 qf[3];
  {
    const int qrow = qbase + w * 16 + i15;
    const u16* qp = q + ((size_t)bh * 1024 + qrow) * 96 + quad * 8;
#pragma unroll
    for (int c = 0; c < 3; ++c) qf[c] = *(const bf16x8*)(qp + c * 32);
  }

  // Staging: 1536 granules/tile (K 768 + V 768), 3 async16 per thread.
  // Granule->global mapping is the inverse of the read-side formulas:
  //   K granule s<768:  c=s>>8, key=(s&255)>>2, qd=s&3 -> row key, octet c*4+(qd^swz(key))
  //   V granule s2:     r=s2>>2, c2=r>=96, d=r-96*c2, qd=s2&3 -> row d, key col c2*32+(qd^swz(d))*8
  const u16* gsrc[3]; int gstep[3];
#pragma unroll
  for (int inst = 0; inst < 3; ++inst) {
    const int s = inst * 512 + tid;
    if (s < 768) {
      const int key6 = (s & 255) >> 2, c = s >> 8;
      const int e = c * 4 + ((s & 3) ^ swz(key6));
      gsrc[inst] = kk + ((size_t)bh * 1024 + key6) * 96 + e * 8;
      gstep[inst] = 64 * 96;                 // +64 key rows per tile
    } else {
      const int s2 = s - 768, r = s2 >> 2;
      const int c2 = (r >= 96), d = r - 96 * c2;
      gsrc[inst] = vT + ((size_t)bh * 96 + d) * 1024 + c2 * 32 + ((s2 & 3) ^ swz(d)) * 8;
      gstep[inst] = 64;                      // +64 key cols per tile
    }
  }

  // prologue: stage tile 0 into buf0 (LDS dest is wave-uniform base + lane*16)
#pragma unroll
  for (int inst = 0; inst < 3; ++inst)
    async16(gsrc[inst], (void*)(smem + (size_t)(inst * 512 + w * 64) * 8));

  f32x4 o[6];
#pragma unroll
  for (int dt = 0; dt < 6; ++dt) o[dt] = (f32x4){0.f, 0.f, 0.f, 0.f};
  float l = 0.f;

  for (int t = 0; t < 16; ++t) {
    __syncthreads();                         // implicit vmcnt(0): buf[t&1] ready
    const u16* KVs = smem + (t & 1) * 12288;
    if (t < 15) {                            // stage t+1 into the other buffer
      u16* dst = smem + ((t + 1) & 1) * 12288;
#pragma unroll
      for (int inst = 0; inst < 3; ++inst) {
        gsrc[inst] += gstep[inst];
        async16(gsrc[inst], (void*)(dst + (size_t)(inst * 512 + w * 64) * 8));
      }
    }
    // ---- S^T phase ----
#pragma unroll
    for (int kt = 0; kt < 4; ++kt) {
      bf16x8 af[3];
#pragma unroll
      for (int c = 0; c < 3; ++c)
        af[c] = *(const bf16x8*)(KVs + ((size_t)((c * 64 + kt * 16 + i15) * 4) + (quad ^ xs)) * 8);
      f32x4 s = (f32x4){0.f, 0.f, 0.f, 0.f};
      __builtin_amdgcn_s_setprio(1);
#pragma unroll
      for (int c = 0; c < 3; ++c)
        s = __builtin_amdgcn_mfma_f32_16x16x32_bf16(af[c], qf[c], s, 0, 0, 0);
      __builtin_amdgcn_s_setprio(0);
      const float e0 = __expf(s[0]), e1 = __expf(s[1]);
      const float e2 = __expf(s[2]), e3 = __expf(s[3]);
      l += (e0 + e1) + (e2 + e3);
      uint2 pk;
      pk.x = (u32)f2bq(e0) | ((u32)f2bq(e1) << 16);
      pk.y = (u32)f2bq(e2) | ((u32)f2bq(e3) << 16);
      const int pg = (kt & 1) * 2 + (quad >> 1);
      *(uint2*)(Pw + (size_t)(((kt >> 1) * 16 + i15) * 4 + (pg ^ xs)) * 8
                    + (quad & 1) * 4) = pk;
    }
    // ---- PV phase ----
#pragma unroll
    for (int c2 = 0; c2 < 2; ++c2) {
      const bf16x8 pa = *(const bf16x8*)(Pw + (size_t)((c2 * 16 + i15) * 4 + (quad ^ xs)) * 8);
      __builtin_amdgcn_s_setprio(1);
#pragma unroll
      for (int dt = 0; dt < 6; ++dt) {
        const bf16x8 vb = *(const bf16x8*)(KVs +
            ((size_t)(768 + (c2 * 96 + dt * 16 + i15) * 4) + (quad ^ xs)) * 8);
        o[dt] = __builtin_amdgcn_mfma_f32_16x16x32_bf16(pa, vb, o[dt], 0, 0, 0);
      }
      __builtin_amdgcn_s_setprio(0);
    }
  }

  l += __shfl_xor(l, 16); l += __shfl_xor(l, 32);
  __syncthreads();                       // all waves done with KVs/Pw regions
  u16* scr = smem + w * 1664;            // 16 rows x stride 104 (per-wave)
#pragma unroll
  for (int r = 0; r < 4; ++r) {
    const float linv = 1.f / __shfl(l, quad * 4 + r);
    const int row16 = quad * 4 + r;
#pragma unroll
    for (int dt = 0; dt < 6; ++dt)
      scr[row16 * 104 + dt * 16 + i15] = f2bq(o[dt][r] * linv);
  }
#pragma unroll
  for (int jj = 0; jj < 3; ++jj) {
    const int id = jj * 64 + lane;
    const int row16 = id / 12, g = id - row16 * 12;
    const int grow = b * 1024 + qbase + w * 16 + row16;
    *(uint4*)(ctx + (size_t)grow * 768 + h * 96 + g * 8) =
        *(const uint4*)(scr + row16 * 104 + g * 8);
  }
}

// ---------------- proj GEMM: 128x64 tiles, ctx @ wT + bias -> out fp32 ------
// 3-buffer counted-vmcnt core, LDS 36KB -> 4 blocks/CU (round-6, kept: total
// improved ~7us from this even as qkv regressed).
__global__ __launch_bounds__(256, 4) void proj_gemm_kernel(
    const u16* __restrict__ ctx, const u16* __restrict__ wT,
    const float* __restrict__ bias, float* __restrict__ out) {
  f32x4 acc[4][2];
  const int bid = blockIdx.x;                 // 768 blocks
  const int xcd = bid & 7, slot = bid >> 3;   // 96 slots per XCD
  const int mb = xcd * 8 + slot / 12, nb = slot % 12;
  const int m0 = mb * 128, n0 = nb * 64;
  gemm_core_c3<64>(ctx, wT, m0, n0, acc);

  const int tid = threadIdx.x, w = tid >> 6, lane = tid & 63;
  const int i15 = lane & 15, quad = lane >> 4;
  const int wm = (w >> 1) * 64, wn = (w & 1) * 32;
#pragma unroll
  for (int jt = 0; jt < 2; ++jt) {
    const int c = n0 + wn + jt * 16 + i15;
    const float bb = bias[c];
#pragma unroll
    for (int it = 0; it < 4; ++it) {
#pragma unroll
      for (int r = 0; r < 4; ++r) {
        const int m = m0 + wm + it * 16 + quad * 4 + r;
        out[(size_t)m * 768 + c] = acc[it][jt][r] + bb;
      }
    }
  }
}

// ---------------- host launcher --------------------------------------------
extern "C" void kernel_launch(void* const* d_in, const int* in_sizes, int n_in,
                              void* d_out, int out_size, void* d_ws, size_t ws_size,
                              hipStream_t stream) {
  const float* x      = (const float*)d_in[0];   // [8,1024,768]
  const float* w_qkv  = (const float*)d_in[1];   // [768,2304]
  const float* temp   = (const float*)d_in[2];   // [8]
  const float* w_proj = (const float*)d_in[3];   // [768,768]
  const float* b_proj = (const float*)d_in[4];   // [768]

  u16* ws      = (u16*)d_ws;
  u16* xb      = ws;                     // 8192*768
  u16* wqkvT   = xb + 6291456;           // 2304*768
  u16* qb      = wqkvT + 1769472;        // 64*1024*96
  u16* kb      = qb + 6291456;
  u16* vTb     = kb + 6291456;           // 64*96*1024 (transposed)
  u16* ctxb    = vTb + 6291456;          // 8192*768
  u16* wprojT  = ctxb + 6291456;         // 768*768

  prep_kernel<<<8448, 256, 0, stream>>>(x, w_qkv, w_proj, xb, wqkvT, wprojT);
  qkv_gemm_kernel<<<768, 256, 0, stream>>>(xb, wqkvT, temp, qb, kb, vTb);
  attn_kernel<<<512, 512, 0, stream>>>(qb, kb, vTb, ctxb);
  proj_gemm_kernel<<<768, 256, 0, stream>>>(ctxb, wprojT, b_proj, (float*)d_out);
}

// Round 11
// 178.240 us; speedup vs baseline: 1.0141x; 1.0049x over previous
//
#include <hip/hip_runtime.h>
#include <hip/hip_bf16.h>
#include <math.h>

typedef __attribute__((ext_vector_type(8))) short bf16x8;   // 8 bf16 = 4 VGPRs (MFMA A/B frag)
typedef __attribute__((ext_vector_type(4))) float f32x4;    // MFMA C/D frag
typedef __attribute__((ext_vector_type(4))) unsigned int u32x4;
typedef unsigned short u16;
typedef unsigned int u32;

// Problem: B=8, N=1024, C=768, H=8, hd=96.  BH=64 combined batch-heads.

__device__ __forceinline__ u16 f2b(float f) {               // fp32 -> bf16 RNE (bit-twiddle)
  u32 u = __float_as_uint(f);
  return (u16)((u + 0x7fffu + ((u >> 16) & 1u)) >> 16);
}
__device__ __forceinline__ u16 f2bq(float f) {              // native v_cvt (RNE on gfx950)
  __hip_bfloat16 h = __float2bfloat16(f);
  return __bfloat16_as_ushort(h);
}
__device__ __forceinline__ float b2f(u16 h) {
  return __uint_as_float(((u32)h) << 16);
}
__device__ __forceinline__ int swz(int m) { return (m ^ (m >> 2)) & 3; }

__device__ __forceinline__ void async16(const void* g, void* l) {
  __builtin_amdgcn_global_load_lds((const __attribute__((address_space(1))) u32*)g,
                                   (__attribute__((address_space(3))) u32*)l, 16, 0, 0);
}

// counted vmcnt waits (immediate must be literal in the asm string)
template<int N> __device__ __forceinline__ void wait_vmcnt();
template<> __device__ __forceinline__ void wait_vmcnt<0>() {
  asm volatile("s_waitcnt vmcnt(0)" ::: "memory");
}
template<> __device__ __forceinline__ void wait_vmcnt<3>() {
  asm volatile("s_waitcnt vmcnt(3)" ::: "memory");
}

// ---------------- prep: cast x, transpose+cast w_qkv and w_proj -------------
__global__ __launch_bounds__(256) void prep_kernel(const float* __restrict__ x,
                                                   const float* __restrict__ w_qkv,
                                                   const float* __restrict__ w_proj,
                                                   u16* __restrict__ xb,
                                                   u16* __restrict__ wqkvT,
                                                   u16* __restrict__ wprojT) {
  __shared__ float t[32][33];
  const int blk = blockIdx.x;
  if (blk < 6144) {                       // cast x -> bf16
    const int idx = blk * 256 + threadIdx.x;
    const float4 v = ((const float4*)x)[idx];
    uint2 o;
    o.x = (u32)f2b(v.x) | ((u32)f2b(v.y) << 16);
    o.y = (u32)f2b(v.z) | ((u32)f2b(v.w) << 16);
    ((uint2*)xb)[idx] = o;
    return;
  }
  const float* in; u16* out; int R, C, bx, by;
  if (blk < 6144 + 1728) {                // w_qkv [768,2304] -> [2304,768]
    const int rem = blk - 6144;
    in = w_qkv; out = wqkvT; R = 768; C = 2304; bx = rem % 72; by = rem / 72;
  } else {                                // w_proj [768,768] -> [768,768]
    const int rem = blk - 6144 - 1728;
    in = w_proj; out = wprojT; R = 768; C = 768; bx = rem % 24; by = rem / 24;
  }
  const int c0 = bx * 32, r0 = by * 32;
  const int tc = threadIdx.x & 31, tr = threadIdx.x >> 5;
#pragma unroll
  for (int j = 0; j < 4; ++j)
    t[tr + j * 8][tc] = in[(size_t)(r0 + tr + j * 8) * C + c0 + tc];
  __syncthreads();
#pragma unroll
  for (int j = 0; j < 4; ++j)
    out[(size_t)(c0 + tr + j * 8) * R + r0 + tc] = f2b(t[tc][tr + j * 8]);
}

// ---------------- BK=32 2-barrier GEMM core (qkv) ---------------------------
// Best measured across six variants (44.3us, FETCH 20MB, occ 23%; dbuf /
// 8-wave / counted-3buf / BK64 all landed 44.4-49.2).  qkv sits at 26% MFMA,
// ~31% LDS BW, ~24% per-CU L2 BW -- the m97-structure latency plateau.  The
// documented escape (8-phase 256-class tile) is grid-infeasible here: 256-wide
// tiles give 288/384 blocks on 256 CUs -> 2-round tail, worse than 768=3/CU.
// Unified LDS granule array: A slots [0,512), B slots [512,512+NT*4).
// Granule XOR swizzle x(m)=(m^(m>>2))&3 keeps frag ds_read_b128 clean while
// staging stays lane-contiguous for global_load_lds (wave-uniform base).
template<int NT>
__device__ __forceinline__ void gemm_core2b(const u16* __restrict__ A,
                                            const u16* __restrict__ Bt,
                                            int m0, int n0, f32x4 acc[4][NT / 32]) {
  constexpr int JT = NT / 32;
  constexpr int NINST = (512 + NT * 4) / 256;
  __shared__ u16 Sm[(512 + NT * 4) * 8];
  const int tid = threadIdx.x;
  const int w = tid >> 6, lane = tid & 63;
  const int i15 = lane & 15, quad = lane >> 4;
  const int wm = (w >> 1) * 64, wn = (w & 1) * (NT / 2);
  const int sw = quad ^ swz(i15);

#pragma unroll
  for (int i = 0; i < 4; ++i)
#pragma unroll
    for (int j = 0; j < JT; ++j) acc[i][j] = (f32x4){0.f, 0.f, 0.f, 0.f};

  for (int k0 = 0; k0 < 768; k0 += 32) {
    __syncthreads();
#pragma unroll
    for (int inst = 0; inst < NINST; ++inst) {
      const int s = inst * 256 + tid;          // granule slot (per lane)
      const u16* src;
      if (inst < 2) {                          // A region (slots < 512)
        const int m = s >> 2, e = s & 3;
        src = A + ((size_t)(m0 + m) * 768 + k0 + (e ^ swz(m)) * 8);
      } else {                                 // B region
        const int s2 = s - 512;
        const int n = s2 >> 2, e = s2 & 3;
        src = Bt + ((size_t)(n0 + n) * 768 + k0 + (e ^ swz(n)) * 8);
      }
      async16(src, (void*)(Sm + (size_t)(inst * 256 + w * 64) * 8));
    }
    __syncthreads();                           // drains vmcnt before reads
    bf16x8 af[4], bf[JT];
#pragma unroll
    for (int i = 0; i < 4; ++i)
      af[i] = *(const bf16x8*)(Sm + ((size_t)(wm + i * 16 + i15) * 4 + sw) * 8);
#pragma unroll
    for (int j = 0; j < JT; ++j)
      bf[j] = *(const bf16x8*)(Sm + ((size_t)512 + (wn + j * 16 + i15) * 4 + sw) * 8);
#pragma unroll
    for (int i = 0; i < 4; ++i)
#pragma unroll
      for (int j = 0; j < JT; ++j)
        acc[i][j] = __builtin_amdgcn_mfma_f32_16x16x32_bf16(af[i], bf[j], acc[i][j], 0, 0, 0);
  }
}

// ---------------- BK=32 3-buffer counted-vmcnt core (proj) ------------------
// Round-6 core, kept for proj where it measurably helped (36KB -> 4 blk/CU).
template<int NT>
__device__ __forceinline__ void gemm_core_c3(const u16* __restrict__ A,
                                             const u16* __restrict__ Bt,
                                             int m0, int n0, f32x4 acc[4][NT / 32]) {
  constexpr int JT = NT / 32;
  constexpr int NG = 512 + NT * 4;               // granules per K-tile
  constexpr int NINST = NG / 256;                // async16 per thread per tile
  __shared__ u16 Sm[3 * NG * 8];
  const int tid = threadIdx.x;
  const int w = tid >> 6, lane = tid & 63;
  const int i15 = lane & 15, quad = lane >> 4;
  const int wm = (w >> 1) * 64, wn = (w & 1) * (NT / 2);
  const int sw = quad ^ swz(i15);

#pragma unroll
  for (int i = 0; i < 4; ++i)
#pragma unroll
    for (int j = 0; j < JT; ++j) acc[i][j] = (f32x4){0.f, 0.f, 0.f, 0.f};

  const u16* gsrc[NINST];
#pragma unroll
  for (int inst = 0; inst < NINST; ++inst) {
    const int s = inst * 256 + tid;              // granule slot (per lane)
    if (s < 512) {                               // A region
      const int m = s >> 2, e = s & 3;
      gsrc[inst] = A + ((size_t)(m0 + m) * 768 + (e ^ swz(m)) * 8);
    } else {                                     // B region
      const int s2 = s - 512;
      const int n = s2 >> 2, e = s2 & 3;
      gsrc[inst] = Bt + ((size_t)(n0 + n) * 768 + (e ^ swz(n)) * 8);
    }
  }

  auto stage = [&](int bsel) {
#pragma unroll
    for (int inst = 0; inst < NINST; ++inst) {
      async16(gsrc[inst], (void*)(Sm + ((size_t)bsel * NG + inst * 256 + w * 64) * 8));
      gsrc[inst] += 32;
    }
  };

  stage(0);
  stage(1);

  for (int t = 0; t < 24; ++t) {
    if (t < 23) wait_vmcnt<NINST>();             // tile t landed; t+1 in flight
    else        wait_vmcnt<0>();                 // last tile: full drain
    __builtin_amdgcn_s_barrier();                // all waves' t-loads visible
    __builtin_amdgcn_sched_barrier(0);           // pin: nothing hoists above
    if (t < 22) stage((t + 2) % 3);              // out back to 2*NINST
    const u16* buf = Sm + (size_t)(t % 3) * NG * 8;
    bf16x8 af[4], bf[JT];
#pragma unroll
    for (int i = 0; i < 4; ++i)
      af[i] = *(const bf16x8*)(buf + ((size_t)(wm + i * 16 + i15) * 4 + sw) * 8);
#pragma unroll
    for (int j = 0; j < JT; ++j)
      bf[j] = *(const bf16x8*)(buf + ((size_t)512 + (wn + j * 16 + i15) * 4 + sw) * 8);
#pragma unroll
    for (int i = 0; i < 4; ++i)
#pragma unroll
      for (int j = 0; j < JT; ++j)
        acc[i][j] = __builtin_amdgcn_mfma_f32_16x16x32_bf16(af[i], bf[j], acc[i][j], 0, 0, 0);
  }
}

// ---------------- qkv GEMM + fused L2norm/temp epilogue ---------------------
// Tile 128x192: N-tile = exactly 2 heads -> each wave owns one head's full
// 96-d rows. Rows live in 16 lanes sharing quad -> sumsq = in-thread over jt
// + shfl_xor(1,2,4,8). q gets temp[h] folded; v written transposed (packed).
__global__ __launch_bounds__(256, 3) void qkv_gemm_kernel(
    const u16* __restrict__ xb, const u16* __restrict__ wT,
    const float* __restrict__ temp,
    u16* __restrict__ q, u16* __restrict__ k, u16* __restrict__ vT) {
  f32x4 acc[4][6];
  const int bid = blockIdx.x;                 // 768 blocks = 3/CU exact
  const int xcd = bid & 7, slot = bid >> 3;   // 96 slots per XCD
  const int mb = xcd * 8 + slot / 12, nb = slot % 12;
  const int m0 = mb * 128, n0 = nb * 192;
  gemm_core2b<192>(xb, wT, m0, n0, acc);

  const int tid = threadIdx.x, w = tid >> 6, lane = tid & 63;
  const int i15 = lane & 15, quad = lane >> 4;
  const int wm = (w >> 1) * 64;
  const int three = nb >> 2;                  // 0=q, 1=k, 2=v
  const int h = ((nb & 3) << 1) + (w & 1);    // wave-uniform head

  if (three < 2) {
    u16* dst = three ? k : q;
    const float sc_extra = three ? 1.f : temp[h];
#pragma unroll
    for (int it = 0; it < 4; ++it) {
#pragma unroll
      for (int r = 0; r < 4; ++r) {
        float s = 0.f;
#pragma unroll
        for (int jt = 0; jt < 6; ++jt) s += acc[it][jt][r] * acc[it][jt][r];
        s += __shfl_xor(s, 1); s += __shfl_xor(s, 2);
        s += __shfl_xor(s, 4); s += __shfl_xor(s, 8);
        const float scale = sc_extra / fmaxf(sqrtf(s), 1e-12f);
        const int m = m0 + wm + it * 16 + quad * 4 + r;
        const int b = m >> 10, n = m & 1023;
        u16* rowp = dst + ((size_t)(b * 8 + h) * 1024 + n) * 96;
#pragma unroll
        for (int jt = 0; jt < 6; ++jt)
          rowp[jt * 16 + i15] = f2b(acc[it][jt][r] * scale);
      }
    }
  } else {
#pragma unroll
    for (int it = 0; it < 4; ++it) {
      const int mb4 = m0 + wm + it * 16 + quad * 4;
      const int b = mb4 >> 10, nbase = mb4 & 1023;
#pragma unroll
      for (int jt = 0; jt < 6; ++jt) {
        const int d = jt * 16 + i15;
        uint2 pk;
        pk.x = (u32)f2b(acc[it][jt][0]) | ((u32)f2b(acc[it][jt][1]) << 16);
        pk.y = (u32)f2b(acc[it][jt][2]) | ((u32)f2b(acc[it][jt][3]) << 16);
        *(uint2*)(vT + ((size_t)(b * 8 + h) * 96 + d) * 1024 + nbase) = pk;
      }
    }
  }
}

// ---------------- fused attention, bf16 MFMA, no-max online softmax ---------
// r3 double-buffered structure (best measured).  128 q-rows/block, grid 512,
// bh = blockIdx&63 (8 q-blocks of one bh share an XCD; K/V L2-resident
// ~3 MB/XCD).  512 threads = 8 waves x 16 q-rows.  global_load_lds staging
// into DOUBLE-BUFFERED KV region, one barrier/tile.
// LDS: 2 x 12288 u16 KV buffers + 8 x 1024 u16 per-wave P = 64 KB -> 2 blk/CU.
// Kept from r10: native v_cvt bf16 (f2bq) in P-pack + epilogue (fewer VALU
// ops, m240).  REMOVED from r10: s_setprio -- rest-decomposition showed the
// r10 attn bundle +2.6us, and m190 says setprio HURTS barrier-lockstep
// structures (our 8-wave per-tile barrier sync), vs m191's +4-7% which was on
// independent-phase 1-wave blocks.
__global__ __launch_bounds__(512, 4) void attn_kernel(
    const u16* __restrict__ q, const u16* __restrict__ kk,
    const u16* __restrict__ vT, u16* __restrict__ ctx) {
  __shared__ u16 smem[32768];   // [0,12288) buf0; [12288,24576) buf1; [24576,32768) P
  const int tid = threadIdx.x, w = tid >> 6, lane = tid & 63;
  const int i15 = lane & 15, quad = lane >> 4;
  const int xs = swz(i15);
  const int bh = blockIdx.x & 63, qbase = (blockIdx.x >> 6) * 128;
  const int b = bh >> 3, h = bh & 7;
  u16* Pw = smem + 24576 + w * 1024;   // per-wave P: 128 granules (16 rows x 64 keys)

  bf16x8 qf[3];
  {
    const int qrow = qbase + w * 16 + i15;
    const u16* qp = q + ((size_t)bh * 1024 + qrow) * 96 + quad * 8;
#pragma unroll
    for (int c = 0; c < 3; ++c) qf[c] = *(const bf16x8*)(qp + c * 32);
  }

  // Staging: 1536 granules/tile (K 768 + V 768), 3 async16 per thread.
  // Granule->global mapping is the inverse of the read-side formulas:
  //   K granule s<768:  c=s>>8, key=(s&255)>>2, qd=s&3 -> row key, octet c*4+(qd^swz(key))
  //   V granule s2:     r=s2>>2, c2=r>=96, d=r-96*c2, qd=s2&3 -> row d, key col c2*32+(qd^swz(d))*8
  const u16* gsrc[3]; int gstep[3];
#pragma unroll
  for (int inst = 0; inst < 3; ++inst) {
    const int s = inst * 512 + tid;
    if (s < 768) {
      const int key6 = (s & 255) >> 2, c = s >> 8;
      const int e = c * 4 + ((s & 3) ^ swz(key6));
      gsrc[inst] = kk + ((size_t)bh * 1024 + key6) * 96 + e * 8;
      gstep[inst] = 64 * 96;                 // +64 key rows per tile
    } else {
      const int s2 = s - 768, r = s2 >> 2;
      const int c2 = (r >= 96), d = r - 96 * c2;
      gsrc[inst] = vT + ((size_t)bh * 96 + d) * 1024 + c2 * 32 + ((s2 & 3) ^ swz(d)) * 8;
      gstep[inst] = 64;                      // +64 key cols per tile
    }
  }

  // prologue: stage tile 0 into buf0 (LDS dest is wave-uniform base + lane*16)
#pragma unroll
  for (int inst = 0; inst < 3; ++inst)
    async16(gsrc[inst], (void*)(smem + (size_t)(inst * 512 + w * 64) * 8));

  f32x4 o[6];
#pragma unroll
  for (int dt = 0; dt < 6; ++dt) o[dt] = (f32x4){0.f, 0.f, 0.f, 0.f};
  float l = 0.f;

  for (int t = 0; t < 16; ++t) {
    __syncthreads();                         // implicit vmcnt(0): buf[t&1] ready
    const u16* KVs = smem + (t & 1) * 12288;
    if (t < 15) {                            // stage t+1 into the other buffer
      u16* dst = smem + ((t + 1) & 1) * 12288;
#pragma unroll
      for (int inst = 0; inst < 3; ++inst) {
        gsrc[inst] += gstep[inst];
        async16(gsrc[inst], (void*)(dst + (size_t)(inst * 512 + w * 64) * 8));
      }
    }
    // ---- S^T phase ----
#pragma unroll
    for (int kt = 0; kt < 4; ++kt) {
      bf16x8 af[3];
#pragma unroll
      for (int c = 0; c < 3; ++c)
        af[c] = *(const bf16x8*)(KVs + ((size_t)((c * 64 + kt * 16 + i15) * 4) + (quad ^ xs)) * 8);
      f32x4 s = (f32x4){0.f, 0.f, 0.f, 0.f};
#pragma unroll
      for (int c = 0; c < 3; ++c)
        s = __builtin_amdgcn_mfma_f32_16x16x32_bf16(af[c], qf[c], s, 0, 0, 0);
      const float e0 = __expf(s[0]), e1 = __expf(s[1]);
      const float e2 = __expf(s[2]), e3 = __expf(s[3]);
      l += (e0 + e1) + (e2 + e3);
      uint2 pk;
      pk.x = (u32)f2bq(e0) | ((u32)f2bq(e1) << 16);
      pk.y = (u32)f2bq(e2) | ((u32)f2bq(e3) << 16);
      const int pg = (kt & 1) * 2 + (quad >> 1);
      *(uint2*)(Pw + (size_t)(((kt >> 1) * 16 + i15) * 4 + (pg ^ xs)) * 8
                    + (quad & 1) * 4) = pk;
    }
    // ---- PV phase ----
#pragma unroll
    for (int c2 = 0; c2 < 2; ++c2) {
      const bf16x8 pa = *(const bf16x8*)(Pw + (size_t)((c2 * 16 + i15) * 4 + (quad ^ xs)) * 8);
#pragma unroll
      for (int dt = 0; dt < 6; ++dt) {
        const bf16x8 vb = *(const bf16x8*)(KVs +
            ((size_t)(768 + (c2 * 96 + dt * 16 + i15) * 4) + (quad ^ xs)) * 8);
        o[dt] = __builtin_amdgcn_mfma_f32_16x16x32_bf16(pa, vb, o[dt], 0, 0, 0);
      }
    }
  }

  l += __shfl_xor(l, 16); l += __shfl_xor(l, 32);
  __syncthreads();                       // all waves done with KVs/Pw regions
  u16* scr = smem + w * 1664;            // 16 rows x stride 104 (per-wave)
#pragma unroll
  for (int r = 0; r < 4; ++r) {
    const float linv = 1.f / __shfl(l, quad * 4 + r);
    const int row16 = quad * 4 + r;
#pragma unroll
    for (int dt = 0; dt < 6; ++dt)
      scr[row16 * 104 + dt * 16 + i15] = f2bq(o[dt][r] * linv);
  }
#pragma unroll
  for (int jj = 0; jj < 3; ++jj) {
    const int id = jj * 64 + lane;
    const int row16 = id / 12, g = id - row16 * 12;
    const int grow = b * 1024 + qbase + w * 16 + row16;
    *(uint4*)(ctx + (size_t)grow * 768 + h * 96 + g * 8) =
        *(const uint4*)(scr + row16 * 104 + g * 8);
  }
}

// ---------------- proj GEMM: 128x64 tiles, ctx @ wT + bias -> out fp32 ------
// 3-buffer counted-vmcnt core, LDS 36KB -> 4 blocks/CU (round-6, kept: total
// improved ~7us from this even as qkv regressed).
__global__ __launch_bounds__(256, 4) void proj_gemm_kernel(
    const u16* __restrict__ ctx, const u16* __restrict__ wT,
    const float* __restrict__ bias, float* __restrict__ out) {
  f32x4 acc[4][2];
  const int bid = blockIdx.x;                 // 768 blocks
  const int xcd = bid & 7, slot = bid >> 3;   // 96 slots per XCD
  const int mb = xcd * 8 + slot / 12, nb = slot % 12;
  const int m0 = mb * 128, n0 = nb * 64;
  gemm_core_c3<64>(ctx, wT, m0, n0, acc);

  const int tid = threadIdx.x, w = tid >> 6, lane = tid & 63;
  const int i15 = lane & 15, quad = lane >> 4;
  const int wm = (w >> 1) * 64, wn = (w & 1) * 32;
#pragma unroll
  for (int jt = 0; jt < 2; ++jt) {
    const int c = n0 + wn + jt * 16 + i15;
    const float bb = bias[c];
#pragma unroll
    for (int it = 0; it < 4; ++it) {
#pragma unroll
      for (int r = 0; r < 4; ++r) {
        const int m = m0 + wm + it * 16 + quad * 4 + r;
        out[(size_t)m * 768 + c] = acc[it][jt][r] + bb;
      }
    }
  }
}

// ---------------- host launcher --------------------------------------------
extern "C" void kernel_launch(void* const* d_in, const int* in_sizes, int n_in,
                              void* d_out, int out_size, void* d_ws, size_t ws_size,
                              hipStream_t stream) {
  const float* x      = (const float*)d_in[0];   // [8,1024,768]
  const float* w_qkv  = (const float*)d_in[1];   // [768,2304]
  const float* temp   = (const float*)d_in[2];   // [8]
  const float* w_proj = (const float*)d_in[3];   // [768,768]
  const float* b_proj = (const float*)d_in[4];   // [768]

  u16* ws      = (u16*)d_ws;
  u16* xb      = ws;                     // 8192*768
  u16* wqkvT   = xb + 6291456;           // 2304*768
  u16* qb      = wqkvT + 1769472;        // 64*1024*96
  u16* kb      = qb + 6291456;
  u16* vTb     = kb + 6291456;           // 64*96*1024 (transposed)
  u16* ctxb    = vTb + 6291456;          // 8192*768
  u16* wprojT  = ctxb + 6291456;         // 768*768

  prep_kernel<<<8448, 256, 0, stream>>>(x, w_qkv, w_proj, xb, wqkvT, wprojT);
  qkv_gemm_kernel<<<768, 256, 0, stream>>>(xb, wqkvT, temp, qb, kb, vTb);
  attn_kernel<<<512, 512, 0, stream>>>(qb, kb, vTb, ctxb);
  proj_gemm_kernel<<<768, 256, 0, stream>>>(ctxb, wprojT, b_proj, (float*)d_out);
}